// Round 8
// baseline (634.935 us; speedup 1.0000x reference)
//
#include <hip/hip_runtime.h>
#include <stdint.h>

#define N_THRESH 100
#define NBINS 101
#define NWORDS 51     // 2 bins per u32 word; per half: [pos:8 | cnt:8]
#define NSLOT 64      // global atomic table slots (blockIdx & 63)
#define SLOT_OFF NBINS
// d_ws layout (u64): [0..100] main hist; [101 + slot*101 + bin] slot table.

// ---------------------------------------------------------------------------
// Kernel 0: zero main hist + slot table (d_ws is poisoned 0xAA every call).
// ---------------------------------------------------------------------------
__global__ void zero_ws_kernel(unsigned long long* __restrict__ ws) {
    int i = blockIdx.x * blockDim.x + threadIdx.x;
    if (i < NBINS + NSLOT * NBINS) ws[i] = 0ull;
}

// ---------------------------------------------------------------------------
// Branch-free exact bin (absmax 0.0 across R1-R7): cnt = searchsorted(
// thresholds, v, 'left'), thresholds[k] = float32(double(k)*0.01).
// e = trunc(fl(v*100)) is within 1 of the answer, so
// cnt = e + (t_e < v) + (t_{e+1} < v) exactly. All in registers.
// ---------------------------------------------------------------------------
__device__ __forceinline__ int bin_of(float v) {
    int e = (int)(v * 100.0f);
    e = e < 0 ? 0 : (e > 99 ? 99 : e);
    double ed = (double)e * 0.01;
    float t0 = (float)ed;
    float t1 = (float)(ed + 0.01);
    int c = e + (t0 < v ? 1 : 0) + (t1 < v ? 1 : 0);
    return c > N_THRESH ? N_THRESH : c;
}

// ---------------------------------------------------------------------------
// Kernel 1: dual-pipe streaming histogram.
// Measured wall (R1-R7): scattered DS retires ~1 lane-op/cyc/CU regardless of
// atomicity/banking/latency -> pure-LDS floor ~2 cyc/element. Split:
//   5/8 of elements -> per-lane private LDS columns (R7 RMW path, race-free,
//       bank = lane mod 32 -> fixed 2-way, no atomics)
//   3/8 of elements -> fire-and-forget global u64 atomics into d_ws slot
//       table (L2 atomic units, independent pipe; slot = blockIdx&63 keeps
//       each slot's lines on one XCD since 64 % 8 == 0)
// LDS packing: word = bin>>1, halves [pos:8|cnt:8]; per-lane per-bin LDS-path
// increments <= 5*4*2 + remainder <= 72 < 255 -> exact.
// ---------------------------------------------------------------------------
__global__ __launch_bounds__(256) void hist_kernel(
        const float* __restrict__ pred,
        const int* __restrict__ gt,
        unsigned long long* __restrict__ ws,
        int n) {
    __shared__ uint32_t hist[4][NWORDS][64];        // 52224 B
    __shared__ uint32_t pcnt[NBINS], ppos[NBINS];   // 808 B

    const int tid  = threadIdx.x;
    const int wave = tid >> 6;
    const int lane = tid & 63;

    // zero this wave's private table (own-wave lanes only: no barrier needed)
    for (int i = lane; i < NWORDS * 64; i += 64) (&hist[wave][0][0])[i] = 0u;
    if (tid < NBINS) { pcnt[tid] = 0u; ppos[tid] = 0u; }

    const int nvec = n >> 2;
    const float4* __restrict__ p4 = (const float4*)pred;
    const int4*   __restrict__ g4 = (const int4*)gt;
    const int gsz = gridDim.x * blockDim.x;
    const int t   = blockIdx.x * blockDim.x + tid;
    unsigned long long* __restrict__ slot =
        ws + SLOT_OFF + (blockIdx.x & (NSLOT - 1)) * NBINS;

    // full superiterations: 8 float4 per thread, positions 0-4 -> LDS RMW,
    // positions 5-7 -> global atomic
    const int nsuper = nvec / (8 * gsz);
    for (int s = 0; s < nsuper; ++s) {
        const int base = s * 8 * gsz + t;
        float4 p[8];
        int4   g[8];
#pragma unroll
        for (int k = 0; k < 8; ++k) {
            p[k] = p4[base + k * gsz];
            g[k] = g4[base + k * gsz];
        }
#pragma unroll
        for (int k = 0; k < 5; ++k) {   // LDS path (DS pipe)
            int c0 = bin_of(p[k].x), c1 = bin_of(p[k].y);
            int c2 = bin_of(p[k].z), c3 = bin_of(p[k].w);
            hist[wave][c0 >> 1][lane] +=
                (1u | ((uint32_t)(g[k].x != 0) << 8)) << ((c0 & 1) * 16);
            hist[wave][c1 >> 1][lane] +=
                (1u | ((uint32_t)(g[k].y != 0) << 8)) << ((c1 & 1) * 16);
            hist[wave][c2 >> 1][lane] +=
                (1u | ((uint32_t)(g[k].z != 0) << 8)) << ((c2 & 1) * 16);
            hist[wave][c3 >> 1][lane] +=
                (1u | ((uint32_t)(g[k].w != 0) << 8)) << ((c3 & 1) * 16);
        }
#pragma unroll
        for (int k = 5; k < 8; ++k) {   // global-atomic path (L2 pipe)
            atomicAdd(&slot[bin_of(p[k].x)],
                      1ull | ((unsigned long long)(g[k].x != 0) << 32));
            atomicAdd(&slot[bin_of(p[k].y)],
                      1ull | ((unsigned long long)(g[k].y != 0) << 32));
            atomicAdd(&slot[bin_of(p[k].z)],
                      1ull | ((unsigned long long)(g[k].z != 0) << 32));
            atomicAdd(&slot[bin_of(p[k].w)],
                      1ull | ((unsigned long long)(g[k].w != 0) << 32));
        }
    }

    // generic remainder float4s (empty for N = 2^25) -> LDS path
    for (int i = nsuper * 8 * gsz + t; i < nvec; i += gsz) {
        float4 p = p4[i];
        int4   g = g4[i];
        int c0 = bin_of(p.x), c1 = bin_of(p.y);
        int c2 = bin_of(p.z), c3 = bin_of(p.w);
        hist[wave][c0 >> 1][lane] +=
            (1u | ((uint32_t)(g.x != 0) << 8)) << ((c0 & 1) * 16);
        hist[wave][c1 >> 1][lane] +=
            (1u | ((uint32_t)(g.y != 0) << 8)) << ((c1 & 1) * 16);
        hist[wave][c2 >> 1][lane] +=
            (1u | ((uint32_t)(g.z != 0) << 8)) << ((c2 & 1) * 16);
        hist[wave][c3 >> 1][lane] +=
            (1u | ((uint32_t)(g.w != 0) << 8)) << ((c3 & 1) * 16);
    }

    // scalar tail (n not multiple of 4) — empty for N = 2^25
    if (blockIdx.x == 0 && tid == 0) {
        for (int k = nvec << 2; k < n; ++k) {
            int c = bin_of(pred[k]);
            hist[0][c >> 1][0] +=
                (1u | ((uint32_t)(gt[k] != 0) << 8)) << ((c & 1) * 16);
        }
    }

    __syncthreads();
    // fold LDS: lane w (<51) sums its wave's word w over 64 columns
    if (lane < NWORDS) {
        uint32_t c0 = 0, p0 = 0, c1 = 0, p1 = 0;
        for (int c = 0; c < 64; ++c) {
            uint32_t v = hist[wave][lane][(c + lane) & 63];
            c0 += v & 0xffu;         p0 += (v >> 8) & 0xffu;
            c1 += (v >> 16) & 0xffu; p1 += v >> 24;
        }
        const int b0 = lane * 2, b1 = lane * 2 + 1;
        atomicAdd(&pcnt[b0], c0);
        atomicAdd(&ppos[b0], p0);
        if (b1 < NBINS) {               // half 1 of word 50 = bin 101: unused
            atomicAdd(&pcnt[b1], c1);
            atomicAdd(&ppos[b1], p1);
        }
    }
    __syncthreads();

    if (tid < NBINS) {
        unsigned long long s =
            ((unsigned long long)ppos[tid] << 32) | (unsigned long long)pcnt[tid];
        if (s) atomicAdd(&ws[tid], s);
    }
}

// ---------------------------------------------------------------------------
// Kernel 2: fold slot table + suffix sums + IoU. One block, trivial cost.
// out[0:100] = thresholds, out[100:200] = ious.
// ---------------------------------------------------------------------------
__global__ void finalize_kernel(const unsigned long long* __restrict__ ws,
                                float* __restrict__ out) {
    __shared__ unsigned long long pos[NBINS], all[NBINS];
    int k = threadIdx.x;
    if (k < NBINS) {
        unsigned long long h = ws[k];
        unsigned long long p = h >> 32, c = h & 0xffffffffull;
        for (int s = 0; s < NSLOT; ++s) {
            unsigned long long v = ws[SLOT_OFF + s * NBINS + k];
            p += v >> 32;
            c += v & 0xffffffffull;
        }
        pos[k] = p;
        all[k] = c;
    }
    __syncthreads();
    if (k < N_THRESH) {
        out[k] = (float)((double)k * 0.01);
        unsigned long long tp = 0, pp = 0, ngt = 0;
        for (int c = k + 1; c <= N_THRESH; ++c) { tp += pos[c]; pp += all[c]; }
        for (int c = 0; c <= N_THRESH; ++c) ngt += pos[c];
        long long uni = (long long)(pp + ngt - tp);   // TP + FP + FN
        double iou = (uni > 0) ? (double)tp / (double)uni : 0.0;
        out[N_THRESH + k] = (float)iou;
    }
}

// ---------------------------------------------------------------------------
extern "C" void kernel_launch(void* const* d_in, const int* in_sizes, int n_in,
                              void* d_out, int out_size, void* d_ws, size_t ws_size,
                              hipStream_t stream) {
    const float* pred = (const float*)d_in[0];
    const int*   gt   = (const int*)d_in[1];
    float* out = (float*)d_out;
    unsigned long long* ws = (unsigned long long*)d_ws;
    int n = in_sizes[0];

    zero_ws_kernel<<<26, 256, 0, stream>>>(ws);   // 6656 >= 101 + 64*101
    // 2048 blocks x 256 threads; 16 float4/thread at N = 2^25 -> 2 exact
    // superiterations (5 LDS + 3 global each). Guard: grow grid so
    // elements/thread <= 64 (keeps 8-bit LDS counters exact).
    int nvec = n >> 2;
    int grid = 2048;
    int need = (nvec + 4095) / 4096;   // threads*16 float4 coverage
    if (need > grid) grid = need;
    hist_kernel<<<grid, 256, 0, stream>>>(pred, gt, ws, n);
    finalize_kernel<<<1, 128, 0, stream>>>(ws, out);
}